// Round 9
// baseline (253.023 us; speedup 1.0000x reference)
//
#include <hip/hip_runtime.h>
#include <math.h>

#define HH 1024
#define WW 1024
#define NCH 16
#define ROWS_PER_BLOCK 8
#define BLOCKS_PER_CH (HH / ROWS_PER_BLOCK) /* 128 */
#define NEG_INF (-INFINITY)

__device__ __forceinline__ bool better_f(float v1, int i1, float v2, int i2) {
    return (v1 > v2) || ((v1 == v2) && (i1 < i2));
}

// Sorted-insert top-8 kept entirely in NAMED registers (no arrays -> no scratch).
#define CSWAP(J, JM) \
    if (better_f(tv##J, ti##J, tv##JM, ti##JM)) { \
        float _fv = tv##J; tv##J = tv##JM; tv##JM = _fv; \
        int _iv = ti##J; ti##J = ti##JM; ti##JM = _iv; }

#define PUSH(VAL, IDX) do { \
    float _pv = (VAL); int _pix = (IDX); \
    if (better_f(_pv, _pix, tv7, ti7)) { \
        tv7 = _pv; ti7 = _pix; \
        CSWAP(7,6) CSWAP(6,5) CSWAP(5,4) CSWAP(4,3) CSWAP(3,2) CSWAP(2,1) CSWAP(1,0) \
    } } while (0)

#define POP() do { \
    tv0=tv1; ti0=ti1; tv1=tv2; ti1=ti2; tv2=tv3; ti2=ti3; tv3=tv4; ti3=ti4; \
    tv4=tv5; ti4=ti5; tv5=tv6; ti5=ti6; tv6=tv7; ti6=ti7; \
    tv7=NEG_INF; ti7=0x7FFFFFFF; } while (0)

#define TOP8_INIT() \
    float tv0=NEG_INF,tv1=NEG_INF,tv2=NEG_INF,tv3=NEG_INF,tv4=NEG_INF,tv5=NEG_INF,tv6=NEG_INF,tv7=NEG_INF; \
    int ti0=0x7FFFFFFF,ti1=0x7FFFFFFF,ti2=0x7FFFFFFF,ti3=0x7FFFFFFF,ti4=0x7FFFFFFF,ti5=0x7FFFFFFF,ti6=0x7FFFFFFF,ti7=0x7FFFFFFF;

// Load one row: center float4 via memory, 2-col halos via intra-wave shuffles
// (wave-edge lanes fetch the 2 scalars from L1 - same lines the neighbor loaded).
#define LOADROW(R, RV, HV) do { \
    const int _r = (R); \
    if (_r < 0 || _r >= HH) { \
        RV = make_float4(NEG_INF, NEG_INF, NEG_INF, NEG_INF); HV = RV; \
    } else { \
        const float* _rp = hmc + (size_t)_r * WW; \
        float4 _M = *(const float4*)(_rp + c0); \
        float _lm2 = __shfl_up(_M.z, 1), _lm1 = __shfl_up(_M.w, 1); \
        float _rp0 = __shfl_down(_M.x, 1), _rp1 = __shfl_down(_M.y, 1); \
        if (lane == 0) { \
            _lm2 = (c0 >= 2) ? _rp[c0 - 2] : NEG_INF; \
            _lm1 = (c0 >= 1) ? _rp[c0 - 1] : NEG_INF; \
        } \
        if (lane == 63) { \
            _rp0 = (c0 + 4 < WW) ? _rp[c0 + 4] : NEG_INF; \
            _rp1 = (c0 + 5 < WW) ? _rp[c0 + 5] : NEG_INF; \
        } \
        float _m01 = fmaxf(_M.x, _M.y), _m23 = fmaxf(_M.z, _M.w); \
        HV.x = fmaxf(fmaxf(_lm2, _lm1), fmaxf(_m01, _M.z)); \
        HV.y = fmaxf(_lm1, fmaxf(_m01, _m23)); \
        HV.z = fmaxf(fmaxf(_m01, _m23), _rp0); \
        HV.w = fmaxf(fmaxf(_M.y, _m23), fmaxf(_rp0, _rp1)); \
        RV = _M; \
    } } while (0)

// ---------------- Kernel A: NMS + per-block top-8 candidates + copy heatmap->out ----
__global__ __launch_bounds__(256) void kA(const float* __restrict__ hm,
                                          float* __restrict__ out,
                                          float* __restrict__ cand_val,
                                          int* __restrict__ cand_idx) {
    const int ch = blockIdx.y;
    const int r0 = blockIdx.x * ROWS_PER_BLOCK;
    const int tid = threadIdx.x;
    const int lane = tid & 63;
    const int c0 = tid * 4;
    const float* hmc = hm + (size_t)ch * (size_t)(HH * WW);
    float* outc = out + (size_t)ch * (size_t)(HH * WW);

    TOP8_INIT();

    float4 raw0, raw1, raw2, raw3, raw4;
    float4 hx0, hx1, hx2, hx3, hx4;
    LOADROW(r0 - 2, raw0, hx0);
    LOADROW(r0 - 1, raw1, hx1);
    LOADROW(r0 + 0, raw2, hx2);
    LOADROW(r0 + 1, raw3, hx3);

#pragma unroll
    for (int i = 0; i < ROWS_PER_BLOCK; ++i) {
        const int r = r0 + i;
        LOADROW(r + 2, raw4, hx4);
        float4 p;
        p.x = fmaxf(fmaxf(fmaxf(hx0.x, hx1.x), fmaxf(hx2.x, hx3.x)), hx4.x);
        p.y = fmaxf(fmaxf(fmaxf(hx0.y, hx1.y), fmaxf(hx2.y, hx3.y)), hx4.y);
        p.z = fmaxf(fmaxf(fmaxf(hx0.z, hx1.z), fmaxf(hx2.z, hx3.z)), hx4.z);
        p.w = fmaxf(fmaxf(fmaxf(hx0.w, hx1.w), fmaxf(hx2.w, hx3.w)), hx4.w);
        float4 cen = raw2;
        *(float4*)(outc + (size_t)r * WW + c0) = cen;  // reweighted base = heatmap copy
        int base = r * WW + c0;
        PUSH((cen.x == p.x) ? cen.x : 0.0f, base + 0);
        PUSH((cen.y == p.y) ? cen.y : 0.0f, base + 1);
        PUSH((cen.z == p.z) ? cen.z : 0.0f, base + 2);
        PUSH((cen.w == p.w) ? cen.w : 0.0f, base + 3);
        raw0 = raw1; raw1 = raw2; raw2 = raw3; raw3 = raw4;
        hx0 = hx1; hx1 = hx2; hx2 = hx3; hx3 = hx4;
    }

    // block-wide exact top-8: 8 rounds of argmax, 1 sync/round (ping-pong LDS).
    __shared__ float swv[2][4];
    __shared__ int swi[2][4];
    const int wid = tid >> 6;
    float wv = 0.f; int wi = 0;
    for (int rnd = 0; rnd < 8; ++rnd) {
        float v = tv0; int ix = ti0;
#pragma unroll
        for (int off = 32; off >= 1; off >>= 1) {
            float ov = __shfl_xor(v, off);
            int oi = __shfl_xor(ix, off);
            if (better_f(ov, oi, v, ix)) { v = ov; ix = oi; }
        }
        if (lane == 0) { swv[rnd & 1][wid] = v; swi[rnd & 1][wid] = ix; }
        __syncthreads();
        float bv = swv[rnd & 1][0]; int bi = swi[rnd & 1][0];
        if (better_f(swv[rnd & 1][1], swi[rnd & 1][1], bv, bi)) { bv = swv[rnd & 1][1]; bi = swi[rnd & 1][1]; }
        if (better_f(swv[rnd & 1][2], swi[rnd & 1][2], bv, bi)) { bv = swv[rnd & 1][2]; bi = swi[rnd & 1][2]; }
        if (better_f(swv[rnd & 1][3], swi[rnd & 1][3], bv, bi)) { bv = swv[rnd & 1][3]; bi = swi[rnd & 1][3]; }
        if (ti0 == bi) POP();  // owner pops
        if (tid == rnd) { wv = bv; wi = bi; }
    }
    const int slotbase = (ch * BLOCKS_PER_CH + blockIdx.x) * 8;
    if (tid < 8) { cand_val[slotbase + tid] = wv; cand_idx[slotbase + tid] = wi; }
}

// ---------------- Kernel BC: blocks 0..15 = per-channel final top-8; 16..143 = pooled mean
__global__ __launch_bounds__(256) void kBC(const float* __restrict__ cand_val,
                                           const int* __restrict__ cand_idx,
                                           const float* __restrict__ fm,
                                           float* __restrict__ out_pc,
                                           int* __restrict__ ws_rows,
                                           int* __restrict__ ws_cols,
                                           float* __restrict__ pooled) {
    const int tid = threadIdx.x;
    if (blockIdx.x < 16) {
        if (tid >= 64) return;
        const int ch = blockIdx.x;
        const int lane = tid;
        TOP8_INIT();
        const float* cv = cand_val + (size_t)ch * 1024 + lane * 16;
        const int* ci = cand_idx + (size_t)ch * 1024 + lane * 16;
#pragma unroll
        for (int j = 0; j < 16; ++j) PUSH(cv[j], ci[j]);

        int mywin = 0;
        for (int rnd = 0; rnd < 8; ++rnd) {
            float v = tv0; int ix = ti0;
#pragma unroll
            for (int off = 32; off >= 1; off >>= 1) {
                float ov = __shfl_xor(v, off);
                int oi = __shfl_xor(ix, off);
                if (better_f(ov, oi, v, ix)) { v = ov; ix = oi; }
            }
            if (ti0 == ix) POP();
            if (lane == rnd) mywin = ix;
        }
        if (lane < 8) {
            int row = mywin >> 10;
            int col = mywin & 1023;
            out_pc[ch * 16 + lane * 2 + 0] = (float)row;
            out_pc[ch * 16 + lane * 2 + 1] = (float)col;
            ws_rows[ch * 8 + lane] = row;
            ws_cols[ch * 8 + lane] = col;
        }
    } else {
        const int c = blockIdx.x - 16;
        float s = 0.f;
        for (int v = 0; v < 16; ++v) {
            const float* p = fm + (size_t)v * 131072 + (size_t)c * 1024;
#pragma unroll
            for (int i = 0; i < 4; ++i) s += p[tid + i * 256];
        }
#pragma unroll
        for (int off = 32; off >= 1; off >>= 1) s += __shfl_xor(s, off);
        __shared__ float red[4];
        if ((tid & 63) == 0) red[tid >> 6] = s;
        __syncthreads();
        if (tid == 0) pooled[c] = (red[0] + red[1] + red[2] + red[3]) * (1.0f / 16384.0f);
    }
}

// ---------------- Kernel DF: per-view fused proto + embeddings + softmax + bias -----
// 16 blocks x 256 threads. Proto computed redundantly per block (tiny).
// Waves 0..3 each handle peaks {w, w+4}. Bias patches added non-atomically with a
// barrier per peak (views are disjoint across blocks; overlaps only within a view).
__global__ __launch_bounds__(256) void kDF(const float* __restrict__ fm,
                                           const int* __restrict__ ws_rows,
                                           const int* __restrict__ ws_cols,
                                           const float* __restrict__ n1w, const float* __restrict__ n1b,
                                           const float* __restrict__ n2w, const float* __restrict__ n2b,
                                           const float* __restrict__ p1w, const float* __restrict__ p1b,
                                           const float* __restrict__ p2w, const float* __restrict__ p2b,
                                           const float* __restrict__ cw, const float* __restrict__ cb,
                                           const float* __restrict__ sw, const float* __restrict__ sb,
                                           const float* __restrict__ prev,
                                           const float* __restrict__ pooled,
                                           float* __restrict__ out_curr,
                                           float* __restrict__ out_ts,
                                           float* __restrict__ out_pe,
                                           float* __restrict__ out_rew) {
    const int v = blockIdx.x;
    const int tid = threadIdx.x;
    const int w = tid >> 6;
    const int j = tid & 63;
    __shared__ float ph1[64], cshr[64], ctx[64], proto_s[64], ts_s[8];
    __shared__ float s_w[4][128], h1_w[4][64];

    // ---- proto (all 4 waves compute identical values; benign identical writes) ----
    float acc = p1b[j];
    for (int c = 0; c < 128; ++c) acc = fmaf(pooled[c], p1w[c * 64 + j], acc);
    ph1[j] = fmaxf(acc, 0.f);
    __syncthreads();
    float e = p2b[j];
    for (int m = 0; m < 64; ++m) e = fmaf(ph1[m], p2w[m * 64 + j], e);
    float sq = e * e;
#pragma unroll
    for (int off = 32; off >= 1; off >>= 1) sq += __shfl_xor(sq, off);
    float cur = e / fmaxf(sqrtf(sq), 1e-12f);
    if (v == 0 && tid < 64) out_curr[j] = cur;
    cshr[j] = cur;
    __syncthreads();
    float a3 = cb[j];
    for (int i = 0; i < 64; ++i) a3 = fmaf(prev[i], cw[i * 64 + j], a3);
    for (int i = 0; i < 64; ++i) a3 = fmaf(cshr[i], cw[(64 + i) * 64 + j], a3);
    ctx[j] = fmaxf(a3, 0.f);
    __syncthreads();
    float a4 = sb[j];
    for (int m = 0; m < 64; ++m) a4 = fmaf(ctx[m], sw[m * 64 + j], a4);
    proto_s[j] = a4;
    __syncthreads();

    // ---- per-wave: 2 peaks each ----
    const float* base = fm + (size_t)v * 131072;
    for (int kk = 0; kk < 2; ++kk) {
        const int k = w + kk * 4;
        int row = ws_rows[v * 8 + k], col = ws_cols[v * 8 + k];
        float ys = (float)row * 0.03125f, xs = (float)col * 0.03125f;
        int y0 = (int)floorf(ys), x0 = (int)floorf(xs);
        float wy = ys - (float)y0, wx = xs - (float)x0;
        float w00 = (1.f - wy) * (1.f - wx), w01 = (1.f - wy) * wx;
        float w10 = wy * (1.f - wx), w11 = wy * wx;

        auto samp = [&](int c) -> float {
            const float* fc = base + (size_t)c * 1024;
            float r = fc[y0 * 32 + x0] * w00;  // y0,x0 always in [0,31]
            if (x0 + 1 < 32) r += fc[y0 * 32 + x0 + 1] * w01;
            if (y0 + 1 < 32) {
                r += fc[(y0 + 1) * 32 + x0] * w10;
                if (x0 + 1 < 32) r += fc[(y0 + 1) * 32 + x0 + 1] * w11;
            }
            return r;
        };
        s_w[w][j] = samp(j);
        s_w[w][j + 64] = samp(j + 64);  // within-wave LDS; DS unit processes in order
        float a = n1b[j];
        for (int c = 0; c < 128; ++c) a = fmaf(s_w[w][c], n1w[c * 64 + j], a);
        h1_w[w][j] = fmaxf(a, 0.f);
        float e2 = n2b[j];
        for (int m = 0; m < 64; ++m) e2 = fmaf(h1_w[w][m], n2w[m * 64 + j], e2);
        float sq2 = e2 * e2;
#pragma unroll
        for (int off = 32; off >= 1; off >>= 1) sq2 += __shfl_xor(sq2, off);
        float emb = e2 / fmaxf(sqrtf(sq2), 1e-12f);
        out_pe[((size_t)v * 8 + k) * 64 + j] = emb;
        float sc = emb * proto_s[j];
#pragma unroll
        for (int off = 32; off >= 1; off >>= 1) sc += __shfl_xor(sc, off);
        if (j == 0) { ts_s[k] = sc; out_ts[v * 8 + k] = sc; }
    }
    __syncthreads();

    // ---- softmax (redundant per thread) + Gaussian bias patches ----
    float m = ts_s[0];
#pragma unroll
    for (int i = 1; i < 8; ++i) m = fmaxf(m, ts_s[i]);
    float sum = 0.f;
#pragma unroll
    for (int i = 0; i < 8; ++i) sum += __expf(ts_s[i] - m);
    const float inv_sum = 1.0f / sum;

    float* oc = out_rew + (size_t)v * (size_t)(HH * WW);
    const float inv2s2 = 1.0f / 18.0f;
    const int RAD = 32, SZ = 65;
    for (int k = 0; k < 8; ++k) {
        const float pw = __expf(ts_s[k] - m) * inv_sum;
        const int r = ws_rows[v * 8 + k], c = ws_cols[v * 8 + k];
        for (int idx = tid; idx < SZ * SZ; idx += 256) {
            int dy = idx / SZ - RAD, dx = idx % SZ - RAD;
            int py = r + dy, px = c + dx;
            if (py >= 0 && py < HH && px >= 0 && px < WW) {
                float d2 = (float)(dy * dy + dx * dx);
                oc[(size_t)py * WW + px] += pw * __expf(-d2 * inv2s2);
            }
        }
        __syncthreads();  // peaks of the same view may overlap
    }
}

extern "C" void kernel_launch(void* const* d_in, const int* in_sizes, int n_in,
                              void* d_out, int out_size, void* d_ws, size_t ws_size,
                              hipStream_t stream) {
    (void)in_sizes; (void)n_in; (void)out_size; (void)ws_size;
    const float* hm   = (const float*)d_in[0];
    const float* fm   = (const float*)d_in[1];
    const float* prev = (const float*)d_in[2];
    const float* n1w  = (const float*)d_in[3];
    const float* n1b  = (const float*)d_in[4];
    const float* n2w  = (const float*)d_in[5];
    const float* n2b  = (const float*)d_in[6];
    const float* p1w  = (const float*)d_in[7];
    const float* p1b  = (const float*)d_in[8];
    const float* p2w  = (const float*)d_in[9];
    const float* p2b  = (const float*)d_in[10];
    const float* cw   = (const float*)d_in[11];
    const float* cb   = (const float*)d_in[12];
    const float* sw   = (const float*)d_in[13];
    const float* sb   = (const float*)d_in[14];
    float* out = (float*)d_out;

    char* ws = (char*)d_ws;
    float* cand_val  = (float*)(ws + 0);        // 16*128*8 f32 = 65536 B
    int*   cand_idx  = (int*)(ws + 65536);      // 65536 B
    int*   ws_rows   = (int*)(ws + 131072);     // 512 B
    int*   ws_cols   = (int*)(ws + 131584);     // 512 B
    float* ws_pooled = (float*)(ws + 132096);   // 512 B

    float* out_rew  = out;                 // 16*1024*1024
    float* out_curr = out + 16777216;      // 64
    float* out_pc   = out + 16777280;      // 256
    float* out_ts   = out + 16777536;      // 128
    float* out_pe   = out + 16777664;      // 8192

    kA<<<dim3(BLOCKS_PER_CH, NCH), 256, 0, stream>>>(hm, out_rew, cand_val, cand_idx);
    kBC<<<144, 256, 0, stream>>>(cand_val, cand_idx, fm, out_pc, ws_rows, ws_cols, ws_pooled);
    kDF<<<NCH, 256, 0, stream>>>(fm, ws_rows, ws_cols, n1w, n1b, n2w, n2b,
                                 p1w, p1b, p2w, p2b, cw, cb, sw, sb, prev, ws_pooled,
                                 out_curr, out_ts, out_pe, out_rew);
}

// Round 11
// 235.611 us; speedup vs baseline: 1.0739x; 1.0739x over previous
//
#include <hip/hip_runtime.h>
#include <math.h>

#define HH 1024
#define WW 1024
#define NCH 16
#define ROWS_PER_BLOCK 8
#define BLOCKS_PER_CH (HH / ROWS_PER_BLOCK) /* 128 */
#define NEG_INF (-INFINITY)

__device__ __forceinline__ bool better_f(float v1, int i1, float v2, int i2) {
    return (v1 > v2) || ((v1 == v2) && (i1 < i2));
}

// Sorted-insert top-8 kept entirely in NAMED registers (no arrays -> no scratch).
#define CSWAP(J, JM) \
    if (better_f(tv##J, ti##J, tv##JM, ti##JM)) { \
        float _fv = tv##J; tv##J = tv##JM; tv##JM = _fv; \
        int _iv = ti##J; ti##J = ti##JM; ti##JM = _iv; }

#define PUSH(VAL, IDX) do { \
    float _pv = (VAL); int _pix = (IDX); \
    if (better_f(_pv, _pix, tv7, ti7)) { \
        tv7 = _pv; ti7 = _pix; \
        CSWAP(7,6) CSWAP(6,5) CSWAP(5,4) CSWAP(4,3) CSWAP(3,2) CSWAP(2,1) CSWAP(1,0) \
    } } while (0)

#define POP() do { \
    tv0=tv1; ti0=ti1; tv1=tv2; ti1=ti2; tv2=tv3; ti2=ti3; tv3=tv4; ti3=ti4; \
    tv4=tv5; ti4=ti5; tv5=tv6; ti5=ti6; tv6=tv7; ti6=ti7; \
    tv7=NEG_INF; ti7=0x7FFFFFFF; } while (0)

#define TOP8_INIT() \
    float tv0=NEG_INF,tv1=NEG_INF,tv2=NEG_INF,tv3=NEG_INF,tv4=NEG_INF,tv5=NEG_INF,tv6=NEG_INF,tv7=NEG_INF; \
    int ti0=0x7FFFFFFF,ti1=0x7FFFFFFF,ti2=0x7FFFFFFF,ti3=0x7FFFFFFF,ti4=0x7FFFFFFF,ti5=0x7FFFFFFF,ti6=0x7FFFFFFF,ti7=0x7FFFFFFF;

// Load one row: center float4 via memory, 2-col halos via intra-wave shuffles
// (wave-edge lanes fetch the 2 scalars from L1 - same lines the neighbor loaded).
#define LOADROW(R, RV, HV) do { \
    const int _r = (R); \
    if (_r < 0 || _r >= HH) { \
        RV = make_float4(NEG_INF, NEG_INF, NEG_INF, NEG_INF); HV = RV; \
    } else { \
        const float* _rp = hmc + (size_t)_r * WW; \
        float4 _M = *(const float4*)(_rp + c0); \
        float _lm2 = __shfl_up(_M.z, 1), _lm1 = __shfl_up(_M.w, 1); \
        float _rp0 = __shfl_down(_M.x, 1), _rp1 = __shfl_down(_M.y, 1); \
        if (lane == 0) { \
            _lm2 = (c0 >= 2) ? _rp[c0 - 2] : NEG_INF; \
            _lm1 = (c0 >= 1) ? _rp[c0 - 1] : NEG_INF; \
        } \
        if (lane == 63) { \
            _rp0 = (c0 + 4 < WW) ? _rp[c0 + 4] : NEG_INF; \
            _rp1 = (c0 + 5 < WW) ? _rp[c0 + 5] : NEG_INF; \
        } \
        float _m01 = fmaxf(_M.x, _M.y), _m23 = fmaxf(_M.z, _M.w); \
        HV.x = fmaxf(fmaxf(_lm2, _lm1), fmaxf(_m01, _M.z)); \
        HV.y = fmaxf(_lm1, fmaxf(_m01, _m23)); \
        HV.z = fmaxf(fmaxf(_m01, _m23), _rp0); \
        HV.w = fmaxf(fmaxf(_M.y, _m23), fmaxf(_rp0, _rp1)); \
        RV = _M; \
    } } while (0)

// ---------------- Kernel A: NMS + per-block top-8 candidates + copy heatmap->out ----
__global__ __launch_bounds__(256) void kA(const float* __restrict__ hm,
                                          float* __restrict__ out,
                                          float* __restrict__ cand_val,
                                          int* __restrict__ cand_idx) {
    const int ch = blockIdx.y;
    const int r0 = blockIdx.x * ROWS_PER_BLOCK;
    const int tid = threadIdx.x;
    const int lane = tid & 63;
    const int c0 = tid * 4;
    const float* hmc = hm + (size_t)ch * (size_t)(HH * WW);
    float* outc = out + (size_t)ch * (size_t)(HH * WW);

    TOP8_INIT();

    float4 raw0, raw1, raw2, raw3, raw4;
    float4 hx0, hx1, hx2, hx3, hx4;
    LOADROW(r0 - 2, raw0, hx0);
    LOADROW(r0 - 1, raw1, hx1);
    LOADROW(r0 + 0, raw2, hx2);
    LOADROW(r0 + 1, raw3, hx3);

#pragma unroll
    for (int i = 0; i < ROWS_PER_BLOCK; ++i) {
        const int r = r0 + i;
        LOADROW(r + 2, raw4, hx4);
        float4 p;
        p.x = fmaxf(fmaxf(fmaxf(hx0.x, hx1.x), fmaxf(hx2.x, hx3.x)), hx4.x);
        p.y = fmaxf(fmaxf(fmaxf(hx0.y, hx1.y), fmaxf(hx2.y, hx3.y)), hx4.y);
        p.z = fmaxf(fmaxf(fmaxf(hx0.z, hx1.z), fmaxf(hx2.z, hx3.z)), hx4.z);
        p.w = fmaxf(fmaxf(fmaxf(hx0.w, hx1.w), fmaxf(hx2.w, hx3.w)), hx4.w);
        float4 cen = raw2;
        *(float4*)(outc + (size_t)r * WW + c0) = cen;  // reweighted base = heatmap copy
        int base = r * WW + c0;
        PUSH((cen.x == p.x) ? cen.x : 0.0f, base + 0);
        PUSH((cen.y == p.y) ? cen.y : 0.0f, base + 1);
        PUSH((cen.z == p.z) ? cen.z : 0.0f, base + 2);
        PUSH((cen.w == p.w) ? cen.w : 0.0f, base + 3);
        raw0 = raw1; raw1 = raw2; raw2 = raw3; raw3 = raw4;
        hx0 = hx1; hx1 = hx2; hx2 = hx3; hx3 = hx4;
    }

    // block-wide exact top-8: 8 rounds of argmax, 1 sync/round (ping-pong LDS).
    __shared__ float swv[2][4];
    __shared__ int swi[2][4];
    const int wid = tid >> 6;
    float wv = 0.f; int wi = 0;
    for (int rnd = 0; rnd < 8; ++rnd) {
        float v = tv0; int ix = ti0;
#pragma unroll
        for (int off = 32; off >= 1; off >>= 1) {
            float ov = __shfl_xor(v, off);
            int oi = __shfl_xor(ix, off);
            if (better_f(ov, oi, v, ix)) { v = ov; ix = oi; }
        }
        if (lane == 0) { swv[rnd & 1][wid] = v; swi[rnd & 1][wid] = ix; }
        __syncthreads();
        float bv = swv[rnd & 1][0]; int bi = swi[rnd & 1][0];
        if (better_f(swv[rnd & 1][1], swi[rnd & 1][1], bv, bi)) { bv = swv[rnd & 1][1]; bi = swi[rnd & 1][1]; }
        if (better_f(swv[rnd & 1][2], swi[rnd & 1][2], bv, bi)) { bv = swv[rnd & 1][2]; bi = swi[rnd & 1][2]; }
        if (better_f(swv[rnd & 1][3], swi[rnd & 1][3], bv, bi)) { bv = swv[rnd & 1][3]; bi = swi[rnd & 1][3]; }
        if (ti0 == bi) POP();  // owner pops
        if (tid == rnd) { wv = bv; wi = bi; }
    }
    const int slotbase = (ch * BLOCKS_PER_CH + blockIdx.x) * 8;
    if (tid < 8) { cand_val[slotbase + tid] = wv; cand_idx[slotbase + tid] = wi; }
}

// ---------------- Kernel BC: blocks 0..15 = per-channel final top-8; 16..143 = pooled mean
__global__ __launch_bounds__(256) void kBC(const float* __restrict__ cand_val,
                                           const int* __restrict__ cand_idx,
                                           const float* __restrict__ fm,
                                           float* __restrict__ out_pc,
                                           int* __restrict__ ws_rows,
                                           int* __restrict__ ws_cols,
                                           float* __restrict__ pooled) {
    const int tid = threadIdx.x;
    if (blockIdx.x < 16) {
        if (tid >= 64) return;
        const int ch = blockIdx.x;
        const int lane = tid;
        TOP8_INIT();
        const float* cv = cand_val + (size_t)ch * 1024 + lane * 16;
        const int* ci = cand_idx + (size_t)ch * 1024 + lane * 16;
#pragma unroll
        for (int j = 0; j < 16; ++j) PUSH(cv[j], ci[j]);

        int mywin = 0;
        for (int rnd = 0; rnd < 8; ++rnd) {
            float v = tv0; int ix = ti0;
#pragma unroll
            for (int off = 32; off >= 1; off >>= 1) {
                float ov = __shfl_xor(v, off);
                int oi = __shfl_xor(ix, off);
                if (better_f(ov, oi, v, ix)) { v = ov; ix = oi; }
            }
            if (ti0 == ix) POP();
            if (lane == rnd) mywin = ix;
        }
        if (lane < 8) {
            int row = mywin >> 10;
            int col = mywin & 1023;
            out_pc[ch * 16 + lane * 2 + 0] = (float)row;
            out_pc[ch * 16 + lane * 2 + 1] = (float)col;
            ws_rows[ch * 8 + lane] = row;
            ws_cols[ch * 8 + lane] = col;
        }
    } else {
        const int c = blockIdx.x - 16;
        float s = 0.f;
        for (int v = 0; v < 16; ++v) {
            const float* p = fm + (size_t)v * 131072 + (size_t)c * 1024;
#pragma unroll
            for (int i = 0; i < 4; ++i) s += p[tid + i * 256];
        }
#pragma unroll
        for (int off = 32; off >= 1; off >>= 1) s += __shfl_xor(s, off);
        __shared__ float red[4];
        if ((tid & 63) == 0) red[tid >> 6] = s;
        __syncthreads();
        if (tid == 0) pooled[c] = (red[0] + red[1] + red[2] + red[3]) * (1.0f / 16384.0f);
    }
}

// ---------------- Kernel D: per-(view,peak) proto(redundant) + embed + score --------
// 128 blocks x 64 threads. Proto/curr recomputed per block (weights L2-resident).
__global__ __launch_bounds__(64) void kD(const float* __restrict__ fm,
                                         const int* __restrict__ ws_rows,
                                         const int* __restrict__ ws_cols,
                                         const float* __restrict__ n1w, const float* __restrict__ n1b,
                                         const float* __restrict__ n2w, const float* __restrict__ n2b,
                                         const float* __restrict__ p1w, const float* __restrict__ p1b,
                                         const float* __restrict__ p2w, const float* __restrict__ p2b,
                                         const float* __restrict__ cw, const float* __restrict__ cb,
                                         const float* __restrict__ sw, const float* __restrict__ sb,
                                         const float* __restrict__ prev,
                                         const float* __restrict__ pooled,
                                         float* __restrict__ out_curr,
                                         float* __restrict__ out_ts,
                                         float* __restrict__ out_pe) {
    const int p = blockIdx.x;
    const int v = p >> 3, k = p & 7;
    const int j = threadIdx.x;
    __shared__ float ph1[64], cshr[64], ctx[64], sbuf[128], h1[64];

    // ---- proto (redundant per block; tiny) ----
    float acc = p1b[j];
    for (int c = 0; c < 128; ++c) acc = fmaf(pooled[c], p1w[c * 64 + j], acc);
    ph1[j] = fmaxf(acc, 0.f);
    __syncthreads();
    float e = p2b[j];
    for (int m = 0; m < 64; ++m) e = fmaf(ph1[m], p2w[m * 64 + j], e);
    float sq = e * e;
#pragma unroll
    for (int off = 32; off >= 1; off >>= 1) sq += __shfl_xor(sq, off);
    float cur = e / fmaxf(sqrtf(sq), 1e-12f);
    if (p == 0) out_curr[j] = cur;
    cshr[j] = cur;
    __syncthreads();
    float a3 = cb[j];
    for (int i = 0; i < 64; ++i) a3 = fmaf(prev[i], cw[i * 64 + j], a3);
    for (int i = 0; i < 64; ++i) a3 = fmaf(cshr[i], cw[(64 + i) * 64 + j], a3);
    ctx[j] = fmaxf(a3, 0.f);
    __syncthreads();
    float a4 = sb[j];
    for (int m = 0; m < 64; ++m) a4 = fmaf(ctx[m], sw[m * 64 + j], a4);
    const float proto_j = a4;

    // ---- bilinear sample + node MLP + score for this (v,k) ----
    const float* base = fm + (size_t)v * 131072;
    int row = ws_rows[v * 8 + k], col = ws_cols[v * 8 + k];
    float ys = (float)row * 0.03125f, xs = (float)col * 0.03125f;
    int y0 = (int)floorf(ys), x0 = (int)floorf(xs);
    float wy = ys - (float)y0, wx = xs - (float)x0;
    float w00 = (1.f - wy) * (1.f - wx), w01 = (1.f - wy) * wx;
    float w10 = wy * (1.f - wx), w11 = wy * wx;

    auto samp = [&](int c) -> float {
        const float* fc = base + (size_t)c * 1024;
        float r = fc[y0 * 32 + x0] * w00;  // y0,x0 always in [0,31]
        if (x0 + 1 < 32) r += fc[y0 * 32 + x0 + 1] * w01;
        if (y0 + 1 < 32) {
            r += fc[(y0 + 1) * 32 + x0] * w10;
            if (x0 + 1 < 32) r += fc[(y0 + 1) * 32 + x0 + 1] * w11;
        }
        return r;
    };
    sbuf[j] = samp(j);
    sbuf[j + 64] = samp(j + 64);
    __syncthreads();
    float a = n1b[j];
    for (int c = 0; c < 128; ++c) a = fmaf(sbuf[c], n1w[c * 64 + j], a);
    h1[j] = fmaxf(a, 0.f);
    __syncthreads();
    float e2 = n2b[j];
    for (int m = 0; m < 64; ++m) e2 = fmaf(h1[m], n2w[m * 64 + j], e2);
    float sq2 = e2 * e2;
#pragma unroll
    for (int off = 32; off >= 1; off >>= 1) sq2 += __shfl_xor(sq2, off);
    float emb = e2 / fmaxf(sqrtf(sq2), 1e-12f);
    out_pe[(size_t)p * 64 + j] = emb;
    float sc = emb * proto_j;
#pragma unroll
    for (int off = 32; off >= 1; off >>= 1) sc += __shfl_xor(sc, off);
    if (j == 0) out_ts[p] = sc;
}

// ---------------- Kernel F: per-(view,peak) Gaussian patch via fire-and-forget atomics
// 128 blocks x 256 threads; softmax recomputed locally from this view's 8 scores.
__global__ __launch_bounds__(256) void kF(const int* __restrict__ ws_rows,
                                          const int* __restrict__ ws_cols,
                                          const float* __restrict__ ts,
                                          float* __restrict__ out) {
    const int p = blockIdx.x;
    const int v = p >> 3, k = p & 7;
    const int tid = threadIdx.x;
    float t0 = ts[v * 8 + 0], t1 = ts[v * 8 + 1], t2 = ts[v * 8 + 2], t3 = ts[v * 8 + 3];
    float t4 = ts[v * 8 + 4], t5 = ts[v * 8 + 5], t6 = ts[v * 8 + 6], t7 = ts[v * 8 + 7];
    float m = fmaxf(fmaxf(fmaxf(t0, t1), fmaxf(t2, t3)), fmaxf(fmaxf(t4, t5), fmaxf(t6, t7)));
    float sum = __expf(t0 - m) + __expf(t1 - m) + __expf(t2 - m) + __expf(t3 - m)
              + __expf(t4 - m) + __expf(t5 - m) + __expf(t6 - m) + __expf(t7 - m);
    float tk = (k == 0) ? t0 : (k == 1) ? t1 : (k == 2) ? t2 : (k == 3) ? t3
             : (k == 4) ? t4 : (k == 5) ? t5 : (k == 6) ? t6 : t7;
    const float pw = __expf(tk - m) / sum;

    const int r = ws_rows[v * 8 + k], c = ws_cols[v * 8 + k];
    float* oc = out + (size_t)v * (size_t)(HH * WW);
    const float inv2s2 = 1.0f / 18.0f;
    const int RAD = 32, SZ = 65;
    for (int idx = tid; idx < SZ * SZ; idx += 256) {
        int dy = idx / SZ - RAD, dx = idx % SZ - RAD;
        int py = r + dy, px = c + dx;
        if (py >= 0 && py < HH && px >= 0 && px < WW) {
            float d2 = (float)(dy * dy + dx * dx);
            atomicAdd(&oc[(size_t)py * WW + px], pw * __expf(-d2 * inv2s2));
        }
    }
}

extern "C" void kernel_launch(void* const* d_in, const int* in_sizes, int n_in,
                              void* d_out, int out_size, void* d_ws, size_t ws_size,
                              hipStream_t stream) {
    (void)in_sizes; (void)n_in; (void)out_size; (void)ws_size;
    const float* hm   = (const float*)d_in[0];
    const float* fm   = (const float*)d_in[1];
    const float* prev = (const float*)d_in[2];
    const float* n1w  = (const float*)d_in[3];
    const float* n1b  = (const float*)d_in[4];
    const float* n2w  = (const float*)d_in[5];
    const float* n2b  = (const float*)d_in[6];
    const float* p1w  = (const float*)d_in[7];
    const float* p1b  = (const float*)d_in[8];
    const float* p2w  = (const float*)d_in[9];
    const float* p2b  = (const float*)d_in[10];
    const float* cw   = (const float*)d_in[11];
    const float* cb   = (const float*)d_in[12];
    const float* sw   = (const float*)d_in[13];
    const float* sb   = (const float*)d_in[14];
    float* out = (float*)d_out;

    char* ws = (char*)d_ws;
    float* cand_val  = (float*)(ws + 0);        // 16*128*8 f32 = 65536 B
    int*   cand_idx  = (int*)(ws + 65536);      // 65536 B
    int*   ws_rows   = (int*)(ws + 131072);     // 512 B
    int*   ws_cols   = (int*)(ws + 131584);     // 512 B
    float* ws_pooled = (float*)(ws + 132096);   // 512 B

    float* out_rew  = out;                 // 16*1024*1024
    float* out_curr = out + 16777216;      // 64
    float* out_pc   = out + 16777280;      // 256
    float* out_ts   = out + 16777536;      // 128
    float* out_pe   = out + 16777664;      // 8192

    kA<<<dim3(BLOCKS_PER_CH, NCH), 256, 0, stream>>>(hm, out_rew, cand_val, cand_idx);
    kBC<<<144, 256, 0, stream>>>(cand_val, cand_idx, fm, out_pc, ws_rows, ws_cols, ws_pooled);
    kD<<<128, 64, 0, stream>>>(fm, ws_rows, ws_cols, n1w, n1b, n2w, n2b,
                               p1w, p1b, p2w, p2b, cw, cb, sw, sb, prev, ws_pooled,
                               out_curr, out_ts, out_pe);
    kF<<<128, 256, 0, stream>>>(ws_rows, ws_cols, out_ts, out_rew);
}

// Round 12
// 197.389 us; speedup vs baseline: 1.2818x; 1.1936x over previous
//
#include <hip/hip_runtime.h>
#include <math.h>

#define HH 1024
#define WW 1024
#define NCH 16
#define ROWS_PER_BLOCK 8
#define BLOCKS_PER_CH (HH / ROWS_PER_BLOCK) /* 128 */
#define NEG_INF (-INFINITY)

__device__ __forceinline__ bool better_f(float v1, int i1, float v2, int i2) {
    return (v1 > v2) || ((v1 == v2) && (i1 < i2));
}

// Sorted-insert top-8 kept entirely in NAMED registers (no arrays -> no scratch).
#define CSWAP(J, JM) \
    if (better_f(tv##J, ti##J, tv##JM, ti##JM)) { \
        float _fv = tv##J; tv##J = tv##JM; tv##JM = _fv; \
        int _iv = ti##J; ti##J = ti##JM; ti##JM = _iv; }

#define PUSH(VAL, IDX) do { \
    float _pv = (VAL); int _pix = (IDX); \
    if (better_f(_pv, _pix, tv7, ti7)) { \
        tv7 = _pv; ti7 = _pix; \
        CSWAP(7,6) CSWAP(6,5) CSWAP(5,4) CSWAP(4,3) CSWAP(3,2) CSWAP(2,1) CSWAP(1,0) \
    } } while (0)

#define POP() do { \
    tv0=tv1; ti0=ti1; tv1=tv2; ti1=ti2; tv2=tv3; ti2=ti3; tv3=tv4; ti3=ti4; \
    tv4=tv5; ti4=ti5; tv5=tv6; ti5=ti6; tv6=tv7; ti6=ti7; \
    tv7=NEG_INF; ti7=0x7FFFFFFF; } while (0)

#define TOP8_INIT() \
    float tv0=NEG_INF,tv1=NEG_INF,tv2=NEG_INF,tv3=NEG_INF,tv4=NEG_INF,tv5=NEG_INF,tv6=NEG_INF,tv7=NEG_INF; \
    int ti0=0x7FFFFFFF,ti1=0x7FFFFFFF,ti2=0x7FFFFFFF,ti3=0x7FFFFFFF,ti4=0x7FFFFFFF,ti5=0x7FFFFFFF,ti6=0x7FFFFFFF,ti7=0x7FFFFFFF;

// Load one row: center float4 via memory, 2-col halos via intra-wave shuffles
// (wave-edge lanes fetch the 2 scalars from L1 - same lines the neighbor loaded).
#define LOADROW(R, RV, HV) do { \
    const int _r = (R); \
    if (_r < 0 || _r >= HH) { \
        RV = make_float4(NEG_INF, NEG_INF, NEG_INF, NEG_INF); HV = RV; \
    } else { \
        const float* _rp = hmc + (size_t)_r * WW; \
        float4 _M = *(const float4*)(_rp + c0); \
        float _lm2 = __shfl_up(_M.z, 1), _lm1 = __shfl_up(_M.w, 1); \
        float _rp0 = __shfl_down(_M.x, 1), _rp1 = __shfl_down(_M.y, 1); \
        if (lane == 0) { \
            _lm2 = (c0 >= 2) ? _rp[c0 - 2] : NEG_INF; \
            _lm1 = (c0 >= 1) ? _rp[c0 - 1] : NEG_INF; \
        } \
        if (lane == 63) { \
            _rp0 = (c0 + 4 < WW) ? _rp[c0 + 4] : NEG_INF; \
            _rp1 = (c0 + 5 < WW) ? _rp[c0 + 5] : NEG_INF; \
        } \
        float _m01 = fmaxf(_M.x, _M.y), _m23 = fmaxf(_M.z, _M.w); \
        HV.x = fmaxf(fmaxf(_lm2, _lm1), fmaxf(_m01, _M.z)); \
        HV.y = fmaxf(_lm1, fmaxf(_m01, _m23)); \
        HV.z = fmaxf(fmaxf(_m01, _m23), _rp0); \
        HV.w = fmaxf(fmaxf(_M.y, _m23), fmaxf(_rp0, _rp1)); \
        RV = _M; \
    } } while (0)

// GEMV with 4 independent accumulator chains (manual ILP; fp reassoc OK at 2% tol).
#define GEMV4(OUT, N, INEXPR, WPTR, LDW, BIAS) do { \
    float _g0 = 0.f, _g1 = 0.f, _g2 = 0.f, _g3 = 0.f; \
    _Pragma("unroll 8") \
    for (int _c = 0; _c < (N); _c += 4) { \
        _g0 = fmaf(INEXPR(_c + 0), (WPTR)[(_c + 0) * (LDW) + j], _g0); \
        _g1 = fmaf(INEXPR(_c + 1), (WPTR)[(_c + 1) * (LDW) + j], _g1); \
        _g2 = fmaf(INEXPR(_c + 2), (WPTR)[(_c + 2) * (LDW) + j], _g2); \
        _g3 = fmaf(INEXPR(_c + 3), (WPTR)[(_c + 3) * (LDW) + j], _g3); \
    } \
    OUT = (BIAS) + ((_g0 + _g1) + (_g2 + _g3)); \
} while (0)

// ---------------- Kernel A: NMS + per-block top-8 candidates + copy heatmap->out ----
__global__ __launch_bounds__(256) void kA(const float* __restrict__ hm,
                                          float* __restrict__ out,
                                          float* __restrict__ cand_val,
                                          int* __restrict__ cand_idx) {
    const int ch = blockIdx.y;
    const int r0 = blockIdx.x * ROWS_PER_BLOCK;
    const int tid = threadIdx.x;
    const int lane = tid & 63;
    const int c0 = tid * 4;
    const float* hmc = hm + (size_t)ch * (size_t)(HH * WW);
    float* outc = out + (size_t)ch * (size_t)(HH * WW);

    TOP8_INIT();

    float4 raw0, raw1, raw2, raw3, raw4;
    float4 hx0, hx1, hx2, hx3, hx4;
    LOADROW(r0 - 2, raw0, hx0);
    LOADROW(r0 - 1, raw1, hx1);
    LOADROW(r0 + 0, raw2, hx2);
    LOADROW(r0 + 1, raw3, hx3);

#pragma unroll
    for (int i = 0; i < ROWS_PER_BLOCK; ++i) {
        const int r = r0 + i;
        LOADROW(r + 2, raw4, hx4);
        float4 p;
        p.x = fmaxf(fmaxf(fmaxf(hx0.x, hx1.x), fmaxf(hx2.x, hx3.x)), hx4.x);
        p.y = fmaxf(fmaxf(fmaxf(hx0.y, hx1.y), fmaxf(hx2.y, hx3.y)), hx4.y);
        p.z = fmaxf(fmaxf(fmaxf(hx0.z, hx1.z), fmaxf(hx2.z, hx3.z)), hx4.z);
        p.w = fmaxf(fmaxf(fmaxf(hx0.w, hx1.w), fmaxf(hx2.w, hx3.w)), hx4.w);
        float4 cen = raw2;
        *(float4*)(outc + (size_t)r * WW + c0) = cen;  // reweighted base = heatmap copy
        int base = r * WW + c0;
        PUSH((cen.x == p.x) ? cen.x : 0.0f, base + 0);
        PUSH((cen.y == p.y) ? cen.y : 0.0f, base + 1);
        PUSH((cen.z == p.z) ? cen.z : 0.0f, base + 2);
        PUSH((cen.w == p.w) ? cen.w : 0.0f, base + 3);
        raw0 = raw1; raw1 = raw2; raw2 = raw3; raw3 = raw4;
        hx0 = hx1; hx1 = hx2; hx2 = hx3; hx3 = hx4;
    }

    // block-wide exact top-8: 8 rounds of argmax, 1 sync/round (ping-pong LDS).
    __shared__ float swv[2][4];
    __shared__ int swi[2][4];
    const int wid = tid >> 6;
    float wv = 0.f; int wi = 0;
    for (int rnd = 0; rnd < 8; ++rnd) {
        float v = tv0; int ix = ti0;
#pragma unroll
        for (int off = 32; off >= 1; off >>= 1) {
            float ov = __shfl_xor(v, off);
            int oi = __shfl_xor(ix, off);
            if (better_f(ov, oi, v, ix)) { v = ov; ix = oi; }
        }
        if (lane == 0) { swv[rnd & 1][wid] = v; swi[rnd & 1][wid] = ix; }
        __syncthreads();
        float bv = swv[rnd & 1][0]; int bi = swi[rnd & 1][0];
        if (better_f(swv[rnd & 1][1], swi[rnd & 1][1], bv, bi)) { bv = swv[rnd & 1][1]; bi = swi[rnd & 1][1]; }
        if (better_f(swv[rnd & 1][2], swi[rnd & 1][2], bv, bi)) { bv = swv[rnd & 1][2]; bi = swi[rnd & 1][2]; }
        if (better_f(swv[rnd & 1][3], swi[rnd & 1][3], bv, bi)) { bv = swv[rnd & 1][3]; bi = swi[rnd & 1][3]; }
        if (ti0 == bi) POP();  // owner pops
        if (tid == rnd) { wv = bv; wi = bi; }
    }
    const int slotbase = (ch * BLOCKS_PER_CH + blockIdx.x) * 8;
    if (tid < 8) { cand_val[slotbase + tid] = wv; cand_idx[slotbase + tid] = wi; }
}

// ---------------- Kernel BC: blocks 0..15 = per-channel final top-8; 16..143 = pooled mean
__global__ __launch_bounds__(256) void kBC(const float* __restrict__ cand_val,
                                           const int* __restrict__ cand_idx,
                                           const float* __restrict__ fm,
                                           float* __restrict__ out_pc,
                                           int* __restrict__ ws_rows,
                                           int* __restrict__ ws_cols,
                                           float* __restrict__ pooled) {
    const int tid = threadIdx.x;
    if (blockIdx.x < 16) {
        if (tid >= 64) return;
        const int ch = blockIdx.x;
        const int lane = tid;
        TOP8_INIT();
        const float* cv = cand_val + (size_t)ch * 1024 + lane * 16;
        const int* ci = cand_idx + (size_t)ch * 1024 + lane * 16;
#pragma unroll
        for (int j = 0; j < 16; ++j) PUSH(cv[j], ci[j]);

        int mywin = 0;
        for (int rnd = 0; rnd < 8; ++rnd) {
            float v = tv0; int ix = ti0;
#pragma unroll
            for (int off = 32; off >= 1; off >>= 1) {
                float ov = __shfl_xor(v, off);
                int oi = __shfl_xor(ix, off);
                if (better_f(ov, oi, v, ix)) { v = ov; ix = oi; }
            }
            if (ti0 == ix) POP();
            if (lane == rnd) mywin = ix;
        }
        if (lane < 8) {
            int row = mywin >> 10;
            int col = mywin & 1023;
            out_pc[ch * 16 + lane * 2 + 0] = (float)row;
            out_pc[ch * 16 + lane * 2 + 1] = (float)col;
            ws_rows[ch * 8 + lane] = row;
            ws_cols[ch * 8 + lane] = col;
        }
    } else {
        const int c = blockIdx.x - 16;
        float s = 0.f;
        for (int v = 0; v < 16; ++v) {
            const float* p = fm + (size_t)v * 131072 + (size_t)c * 1024;
#pragma unroll
            for (int i = 0; i < 4; ++i) s += p[tid + i * 256];
        }
#pragma unroll
        for (int off = 32; off >= 1; off >>= 1) s += __shfl_xor(s, off);
        __shared__ float red[4];
        if ((tid & 63) == 0) red[tid >> 6] = s;
        __syncthreads();
        if (tid == 0) pooled[c] = (red[0] + red[1] + red[2] + red[3]) * (1.0f / 16384.0f);
    }
}

// ---------------- Kernel P: proto computed ONCE (1 block, 64 threads, 4-way ILP) ----
__global__ __launch_bounds__(64) void kP(const float* __restrict__ pooled,
                                         const float* __restrict__ prev,
                                         const float* __restrict__ p1w, const float* __restrict__ p1b,
                                         const float* __restrict__ p2w, const float* __restrict__ p2b,
                                         const float* __restrict__ cw, const float* __restrict__ cb,
                                         const float* __restrict__ sw, const float* __restrict__ sb,
                                         float* __restrict__ out_curr,
                                         float* __restrict__ ws_proto) {
    const int j = threadIdx.x;
    __shared__ float ph1[64], cshr[64], ctx[64];
#define IN_POOL(C) pooled[C]
#define IN_PH1(C) ph1[C]
#define IN_PREV(C) prev[C]
#define IN_CSHR(C) cshr[C]
#define IN_CTX(C) ctx[C]
    float t;
    GEMV4(t, 128, IN_POOL, p1w, 64, p1b[j]);
    ph1[j] = fmaxf(t, 0.f);
    __syncthreads();
    float e;
    GEMV4(e, 64, IN_PH1, p2w, 64, p2b[j]);
    float sq = e * e;
#pragma unroll
    for (int off = 32; off >= 1; off >>= 1) sq += __shfl_xor(sq, off);
    float cur = e / fmaxf(sqrtf(sq), 1e-12f);
    out_curr[j] = cur;
    cshr[j] = cur;
    __syncthreads();
    float c1, c2;
    GEMV4(c1, 64, IN_PREV, cw, 64, cb[j]);
    GEMV4(c2, 64, IN_CSHR, (cw + 64 * 64), 64, 0.f);
    ctx[j] = fmaxf(c1 + c2, 0.f);
    __syncthreads();
    float pr;
    GEMV4(pr, 64, IN_CTX, sw, 64, sb[j]);
    ws_proto[j] = pr;
}

// ---------------- Kernel D: per-(view,peak) bilinear sample + node MLP + score ------
// 128 blocks x 64 threads; GEMVs use 4-way accumulator ILP to break serial chains.
__global__ __launch_bounds__(64) void kD(const float* __restrict__ fm,
                                         const int* __restrict__ ws_rows,
                                         const int* __restrict__ ws_cols,
                                         const float* __restrict__ n1w, const float* __restrict__ n1b,
                                         const float* __restrict__ n2w, const float* __restrict__ n2b,
                                         const float* __restrict__ ws_proto,
                                         float* __restrict__ out_ts,
                                         float* __restrict__ out_pe) {
    const int p = blockIdx.x;
    const int v = p >> 3, k = p & 7;
    const int j = threadIdx.x;
    __shared__ float sbuf[128], h1[64];

    const float* base = fm + (size_t)v * 131072;
    int row = ws_rows[v * 8 + k], col = ws_cols[v * 8 + k];
    float ys = (float)row * 0.03125f, xs = (float)col * 0.03125f;
    int y0 = (int)floorf(ys), x0 = (int)floorf(xs);
    float wy = ys - (float)y0, wx = xs - (float)x0;
    float w00 = (1.f - wy) * (1.f - wx), w01 = (1.f - wy) * wx;
    float w10 = wy * (1.f - wx), w11 = wy * wx;

    auto samp = [&](int c) -> float {
        const float* fc = base + (size_t)c * 1024;
        float r = fc[y0 * 32 + x0] * w00;  // y0,x0 always in [0,31]
        if (x0 + 1 < 32) r += fc[y0 * 32 + x0 + 1] * w01;
        if (y0 + 1 < 32) {
            r += fc[(y0 + 1) * 32 + x0] * w10;
            if (x0 + 1 < 32) r += fc[(y0 + 1) * 32 + x0 + 1] * w11;
        }
        return r;
    };
    sbuf[j] = samp(j);
    sbuf[j + 64] = samp(j + 64);
    __syncthreads();
#define IN_SBUF(C) sbuf[C]
#define IN_H1(C) h1[C]
    float a;
    GEMV4(a, 128, IN_SBUF, n1w, 64, n1b[j]);
    h1[j] = fmaxf(a, 0.f);
    __syncthreads();
    float e2;
    GEMV4(e2, 64, IN_H1, n2w, 64, n2b[j]);
    float sq2 = e2 * e2;
#pragma unroll
    for (int off = 32; off >= 1; off >>= 1) sq2 += __shfl_xor(sq2, off);
    float emb = e2 / fmaxf(sqrtf(sq2), 1e-12f);
    out_pe[(size_t)p * 64 + j] = emb;
    float sc = emb * ws_proto[j];
#pragma unroll
    for (int off = 32; off >= 1; off >>= 1) sc += __shfl_xor(sc, off);
    if (j == 0) out_ts[p] = sc;
}

// ---------------- Kernel F: per-(view,peak) Gaussian patch via fire-and-forget atomics
// 128 blocks x 256 threads; softmax recomputed locally from this view's 8 scores.
__global__ __launch_bounds__(256) void kF(const int* __restrict__ ws_rows,
                                          const int* __restrict__ ws_cols,
                                          const float* __restrict__ ts,
                                          float* __restrict__ out) {
    const int p = blockIdx.x;
    const int v = p >> 3, k = p & 7;
    const int tid = threadIdx.x;
    float t0 = ts[v * 8 + 0], t1 = ts[v * 8 + 1], t2 = ts[v * 8 + 2], t3 = ts[v * 8 + 3];
    float t4 = ts[v * 8 + 4], t5 = ts[v * 8 + 5], t6 = ts[v * 8 + 6], t7 = ts[v * 8 + 7];
    float m = fmaxf(fmaxf(fmaxf(t0, t1), fmaxf(t2, t3)), fmaxf(fmaxf(t4, t5), fmaxf(t6, t7)));
    float sum = __expf(t0 - m) + __expf(t1 - m) + __expf(t2 - m) + __expf(t3 - m)
              + __expf(t4 - m) + __expf(t5 - m) + __expf(t6 - m) + __expf(t7 - m);
    float tk = (k == 0) ? t0 : (k == 1) ? t1 : (k == 2) ? t2 : (k == 3) ? t3
             : (k == 4) ? t4 : (k == 5) ? t5 : (k == 6) ? t6 : t7;
    const float pw = __expf(tk - m) / sum;

    const int r = ws_rows[v * 8 + k], c = ws_cols[v * 8 + k];
    float* oc = out + (size_t)v * (size_t)(HH * WW);
    const float inv2s2 = 1.0f / 18.0f;
    const int RAD = 32, SZ = 65;
    for (int idx = tid; idx < SZ * SZ; idx += 256) {
        int dy = idx / SZ - RAD, dx = idx % SZ - RAD;
        int py = r + dy, px = c + dx;
        if (py >= 0 && py < HH && px >= 0 && px < WW) {
            float d2 = (float)(dy * dy + dx * dx);
            atomicAdd(&oc[(size_t)py * WW + px], pw * __expf(-d2 * inv2s2));
        }
    }
}

extern "C" void kernel_launch(void* const* d_in, const int* in_sizes, int n_in,
                              void* d_out, int out_size, void* d_ws, size_t ws_size,
                              hipStream_t stream) {
    (void)in_sizes; (void)n_in; (void)out_size; (void)ws_size;
    const float* hm   = (const float*)d_in[0];
    const float* fm   = (const float*)d_in[1];
    const float* prev = (const float*)d_in[2];
    const float* n1w  = (const float*)d_in[3];
    const float* n1b  = (const float*)d_in[4];
    const float* n2w  = (const float*)d_in[5];
    const float* n2b  = (const float*)d_in[6];
    const float* p1w  = (const float*)d_in[7];
    const float* p1b  = (const float*)d_in[8];
    const float* p2w  = (const float*)d_in[9];
    const float* p2b  = (const float*)d_in[10];
    const float* cw   = (const float*)d_in[11];
    const float* cb   = (const float*)d_in[12];
    const float* sw   = (const float*)d_in[13];
    const float* sb   = (const float*)d_in[14];
    float* out = (float*)d_out;

    char* ws = (char*)d_ws;
    float* cand_val  = (float*)(ws + 0);        // 16*128*8 f32 = 65536 B
    int*   cand_idx  = (int*)(ws + 65536);      // 65536 B
    int*   ws_rows   = (int*)(ws + 131072);     // 512 B
    int*   ws_cols   = (int*)(ws + 131584);     // 512 B
    float* ws_pooled = (float*)(ws + 132096);   // 512 B
    float* ws_proto  = (float*)(ws + 132608);   // 256 B

    float* out_rew  = out;                 // 16*1024*1024
    float* out_curr = out + 16777216;      // 64
    float* out_pc   = out + 16777280;      // 256
    float* out_ts   = out + 16777536;      // 128
    float* out_pe   = out + 16777664;      // 8192

    kA<<<dim3(BLOCKS_PER_CH, NCH), 256, 0, stream>>>(hm, out_rew, cand_val, cand_idx);
    kBC<<<144, 256, 0, stream>>>(cand_val, cand_idx, fm, out_pc, ws_rows, ws_cols, ws_pooled);
    kP<<<1, 64, 0, stream>>>(ws_pooled, prev, p1w, p1b, p2w, p2b, cw, cb, sw, sb,
                             out_curr, ws_proto);
    kD<<<128, 64, 0, stream>>>(fm, ws_rows, ws_cols, n1w, n1b, n2w, n2b, ws_proto,
                               out_ts, out_pe);
    kF<<<128, 256, 0, stream>>>(ws_rows, ws_cols, out_ts, out_rew);
}